// Round 18
// baseline (180.623 us; speedup 1.0000x reference)
//
#include <hip/hip_runtime.h>

typedef __attribute__((__ext_vector_type__(4))) float f32x4;
typedef __attribute__((__ext_vector_type__(16))) float f32x16;
typedef __attribute__((__ext_vector_type__(8))) __bf16 bf16x8;
typedef __attribute__((__ext_vector_type__(8))) unsigned short u16x8;
typedef __attribute__((__ext_vector_type__(4))) unsigned int u32x4;

#define AS1 __attribute__((address_space(1)))
#define AS3 __attribute__((address_space(3)))

#define SC 0.18033688011112042f   // log2(e)/8
#define MSC 5.7707801635558535f   // 32*SC

__device__ __forceinline__ unsigned short f2bf(float f) {
  unsigned int u = __float_as_uint(f);
  u += 0x7FFFu + ((u >> 16) & 1u);   // RNE
  return (unsigned short)(u >> 16);
}
__device__ __forceinline__ float bf2f(unsigned short u) {
  return __uint_as_float((unsigned int)u << 16);
}
__device__ __forceinline__ unsigned int packtrunc(float lo, float hi) {
  return (__float_as_uint(hi) & 0xFFFF0000u) | (__float_as_uint(lo) >> 16);
}

// ---------------- fused cast fp32 -> bf16 (all 6 tensors, one dispatch) -----
__global__ void cast_all(const float* __restrict__ q, const float* __restrict__ c,
                         const float* __restrict__ wq, const float* __restrict__ wk,
                         const float* __restrict__ wv, const float* __restrict__ wo,
                         unsigned short* __restrict__ qb, unsigned short* __restrict__ cb,
                         unsigned short* __restrict__ wqb, unsigned short* __restrict__ wkb,
                         unsigned short* __restrict__ wvb, unsigned short* __restrict__ wob) {
  const int blk = blockIdx.x;
  const float* s; unsigned short* d; int off;
  if (blk < 4096)        { s = q;  d = qb;  off = blk; }
  else if (blk < 12288)  { s = c;  d = cb;  off = blk - 4096; }
  else if (blk < 13312)  { s = wq; d = wqb; off = blk - 12288; }
  else if (blk < 14336)  { s = wk; d = wkb; off = blk - 13312; }
  else if (blk < 15360)  { s = wv; d = wvb; off = blk - 14336; }
  else                   { s = wo; d = wob; off = blk - 15360; }
  const long i = ((long)off * 256 + threadIdx.x) * 4;
  float4 v = *reinterpret_cast<const float4*>(s + i);
  ushort4 o;
  o.x = f2bf(v.x); o.y = f2bf(v.y); o.z = f2bf(v.z); o.w = f2bf(v.w);
  *reinterpret_cast<ushort4*>(d + i) = o;
}

// ---------------- Q projection: 128x128, 512 threads, PRE-SCALED by SC ------
__global__ __launch_bounds__(512) void proj_q(const unsigned short* __restrict__ A,
                                              const unsigned short* __restrict__ Bt,
                                              unsigned short* __restrict__ C) {
  const int raw = blockIdx.x;
  const int bid = (raw & 7) * 32 + (raw >> 3);    // XCD remap (256 = 8*32)
  const int m0 = (bid >> 3) << 7, n0 = (bid & 7) << 7;
  __shared__ __align__(16) unsigned short As[128 * 32];
  __shared__ __align__(16) unsigned short Bs[128 * 32];
  const int tid = threadIdx.x, lane = tid & 63, wid = tid >> 6;
  const int fr = lane & 15, fg = lane >> 4;
  const int wr = wid >> 2, wc = wid & 3;
  const int srow = tid >> 2;
  const int scol = (tid & 3) * 8;
  const unsigned short* a0 = A + (long)(m0 + srow) * 1024 + scol;
  const unsigned short* b0 = Bt + (long)(n0 + srow) * 1024 + scol;

  f32x4 acc[4][2];
#pragma unroll
  for (int m = 0; m < 4; ++m)
#pragma unroll
    for (int n = 0; n < 2; ++n) acc[m][n] = {0.f, 0.f, 0.f, 0.f};

  for (int k0 = 0; k0 < 1024; k0 += 32) {
    __builtin_amdgcn_global_load_lds((const AS1 void*)(a0 + k0),
                                     (AS3 void*)(As + wid * 512), 16, 0, 0);
    __builtin_amdgcn_global_load_lds((const AS1 void*)(b0 + k0),
                                     (AS3 void*)(Bs + wid * 512), 16, 0, 0);
    __syncthreads();
    bf16x8 af[4], bfr[2];
#pragma unroll
    for (int m = 0; m < 4; ++m)
      af[m] = *reinterpret_cast<const bf16x8*>(&As[(wr * 64 + m * 16 + fr) * 32 + fg * 8]);
#pragma unroll
    for (int n = 0; n < 2; ++n)
      bfr[n] = *reinterpret_cast<const bf16x8*>(&Bs[(wc * 32 + n * 16 + fr) * 32 + fg * 8]);
#pragma unroll
    for (int m = 0; m < 4; ++m)
#pragma unroll
      for (int n = 0; n < 2; ++n)
        acc[m][n] = __builtin_amdgcn_mfma_f32_16x16x32_bf16(af[m], bfr[n], acc[m][n], 0, 0, 0);
    __syncthreads();
  }

#pragma unroll
  for (int m = 0; m < 4; ++m) {
    const int row = m0 + wr * 64 + m * 16 + fg * 4;
#pragma unroll
    for (int n = 0; n < 2; ++n) {
      const int col = n0 + wc * 32 + n * 16 + fr;
#pragma unroll
      for (int r = 0; r < 4; ++r)
        C[(long)(row + r) * 1024 + col] = f2bf(acc[m][n][r] * SC);
    }
  }
}

// ---------------- fused K+V projection: shared A-tile, two B-tiles ----------
// 512 blocks; each computes a 128x128 K-tile AND V-tile from one A staging.
// 3 global_load_lds per K-step (vs 4 across two separate blocks); 16 MFMA
// per wave per barrier-pair (2x the m97 structure) -> barrier drain amortized.
__global__ __launch_bounds__(512) void proj_kv(const unsigned short* __restrict__ cb,
                                               const unsigned short* __restrict__ wkb,
                                               const unsigned short* __restrict__ wvb,
                                               unsigned short* __restrict__ Kb,
                                               unsigned short* __restrict__ Vt) {
  const int raw = blockIdx.x;
  const int bid = (raw & 7) * 64 + (raw >> 3);    // XCD remap (512 = 8*64)
  const int m0 = (bid >> 3) << 7, n0 = (bid & 7) << 7;
  __shared__ __align__(16) unsigned short As[128 * 32];
  __shared__ __align__(16) unsigned short BsK[128 * 32];
  __shared__ __align__(16) unsigned short BsV[128 * 32];
  const int tid = threadIdx.x, lane = tid & 63, wid = tid >> 6;
  const int fr = lane & 15, fg = lane >> 4;
  const int wr = wid >> 2, wc = wid & 3;
  const int srow = tid >> 2;
  const int scol = (tid & 3) * 8;
  const unsigned short* a0 = cb + (long)(m0 + srow) * 1024 + scol;
  const unsigned short* bk0 = wkb + (long)(n0 + srow) * 1024 + scol;
  const unsigned short* bv0 = wvb + (long)(n0 + srow) * 1024 + scol;

  f32x4 aK[4][2], aV[4][2];
#pragma unroll
  for (int m = 0; m < 4; ++m)
#pragma unroll
    for (int n = 0; n < 2; ++n) {
      aK[m][n] = {0.f, 0.f, 0.f, 0.f};
      aV[m][n] = {0.f, 0.f, 0.f, 0.f};
    }

  for (int k0 = 0; k0 < 1024; k0 += 32) {
    __builtin_amdgcn_global_load_lds((const AS1 void*)(a0 + k0),
                                     (AS3 void*)(As + wid * 512), 16, 0, 0);
    __builtin_amdgcn_global_load_lds((const AS1 void*)(bk0 + k0),
                                     (AS3 void*)(BsK + wid * 512), 16, 0, 0);
    __builtin_amdgcn_global_load_lds((const AS1 void*)(bv0 + k0),
                                     (AS3 void*)(BsV + wid * 512), 16, 0, 0);
    __syncthreads();
    bf16x8 af[4], bK[2], bV[2];
#pragma unroll
    for (int m = 0; m < 4; ++m)
      af[m] = *reinterpret_cast<const bf16x8*>(&As[(wr * 64 + m * 16 + fr) * 32 + fg * 8]);
#pragma unroll
    for (int n = 0; n < 2; ++n) {
      bK[n] = *reinterpret_cast<const bf16x8*>(&BsK[(wc * 32 + n * 16 + fr) * 32 + fg * 8]);
      bV[n] = *reinterpret_cast<const bf16x8*>(&BsV[(wc * 32 + n * 16 + fr) * 32 + fg * 8]);
    }
#pragma unroll
    for (int m = 0; m < 4; ++m)
#pragma unroll
      for (int n = 0; n < 2; ++n) {
        aK[m][n] = __builtin_amdgcn_mfma_f32_16x16x32_bf16(af[m], bK[n], aK[m][n], 0, 0, 0);
        aV[m][n] = __builtin_amdgcn_mfma_f32_16x16x32_bf16(af[m], bV[n], aV[m][n], 0, 0, 0);
      }
    __syncthreads();
  }

  // K epilogue: row-major bf16
#pragma unroll
  for (int m = 0; m < 4; ++m) {
    const int row = m0 + wr * 64 + m * 16 + fg * 4;
#pragma unroll
    for (int n = 0; n < 2; ++n) {
      const int col = n0 + wc * 32 + n * 16 + fr;
#pragma unroll
      for (int r = 0; r < 4; ++r)
        Kb[(long)(row + r) * 1024 + col] = f2bf(aK[m][n][r]);
    }
  }
  // V epilogue: V^T layout, token rows contiguous along Tc
#pragma unroll
  for (int m = 0; m < 4; ++m) {
    const int row = m0 + wr * 64 + m * 16 + fg * 4;  // token row in B*Tc
    const int bb = row >> 12, t = row & 4095;
#pragma unroll
    for (int n = 0; n < 2; ++n) {
      const int col = n0 + wc * 32 + n * 16 + fr;    // h*64 + d
      ushort4 o;
      o.x = f2bf(aV[m][n][0]); o.y = f2bf(aV[m][n][1]);
      o.z = f2bf(aV[m][n][2]); o.w = f2bf(aV[m][n][3]);
      *reinterpret_cast<ushort4*>(&Vt[((long)(bb * 1024 + col)) * 4096 + t]) = o;
    }
  }
}

// ---------------- O projection, 128x64 tiles (fp32 out -> d_out) ------------
__global__ __launch_bounds__(512) void gemm_o(const unsigned short* __restrict__ A,
                                              const unsigned short* __restrict__ Bt,
                                              float* __restrict__ C) {
  const int raw = blockIdx.x;
  const int bid = (raw & 7) * 64 + (raw >> 3);    // XCD remap (512 = 8*64)
  const int m0 = (bid >> 4) << 7;                 // 32 m-tiles of 128
  const int n0 = (bid & 15) << 6;                 // 16 n-tiles of 64
  __shared__ __align__(16) unsigned short As[128 * 32];
  __shared__ __align__(16) unsigned short Bs[64 * 32];
  const int tid = threadIdx.x, lane = tid & 63, wid = tid >> 6;
  const int fr = lane & 15, fg = lane >> 4;
  const int wr = wid >> 2, wc = wid & 3;
  const int srow = tid >> 2;            // 0..127
  const int scol = (tid & 3) * 8;
  const unsigned short* a0 = A + (long)(m0 + srow) * 1024 + scol;
  const unsigned short* b0 = Bt + (long)(n0 + srow) * 1024 + scol;  // used iff wid<4

  f32x4 acc[4];
#pragma unroll
  for (int m = 0; m < 4; ++m) acc[m] = {0.f, 0.f, 0.f, 0.f};

  for (int k0 = 0; k0 < 1024; k0 += 32) {
    __builtin_amdgcn_global_load_lds((const AS1 void*)(a0 + k0),
                                     (AS3 void*)(As + wid * 512), 16, 0, 0);
    if (wid < 4)
      __builtin_amdgcn_global_load_lds((const AS1 void*)(b0 + k0),
                                       (AS3 void*)(Bs + wid * 512), 16, 0, 0);
    __syncthreads();
    bf16x8 af[4], bfr;
#pragma unroll
    for (int m = 0; m < 4; ++m)
      af[m] = *reinterpret_cast<const bf16x8*>(&As[(wr * 64 + m * 16 + fr) * 32 + fg * 8]);
    bfr = *reinterpret_cast<const bf16x8*>(&Bs[(wc * 16 + fr) * 32 + fg * 8]);
#pragma unroll
    for (int m = 0; m < 4; ++m)
      acc[m] = __builtin_amdgcn_mfma_f32_16x16x32_bf16(af[m], bfr, acc[m], 0, 0, 0);
    __syncthreads();
  }

#pragma unroll
  for (int m = 0; m < 4; ++m) {
    const int row = m0 + wr * 64 + m * 16 + fg * 4;
    const int col = n0 + wc * 16 + fr;
#pragma unroll
    for (int r = 0; r < 4; ++r)
      C[(long)(row + r) * 1024 + col] = acc[m][r];
  }
}

// ---------------- flash attention: QBLK=256 (8 waves), reg-staged, dbuf -----
// (unchanged from R13: 78.4 us, 0.88 PF)
__global__ __launch_bounds__(512, 4) void flash_attn(const unsigned short* __restrict__ Q,
                                                     const unsigned short* __restrict__ Kb,
                                                     const unsigned short* __restrict__ Vt,
                                                     unsigned short* __restrict__ Op,
                                                     float* __restrict__ Lp) {
  const int tid = threadIdx.x, lane = tid & 63, wid = tid >> 6;
  const int raw = (int)blockIdx.x;
  const int blk = (raw & 7) * 64 + (raw >> 3);    // XCD remap (512 = 8*64)
  const int kvh = blk & 1;
  const int qt = (blk >> 1) & 7;
  const int h = (blk >> 4) & 15;
  const int b = blk >> 8;
  const int q0 = qt * 256;
  const int l = lane & 31, hi = lane >> 5, l7 = l & 7;

  __shared__ __align__(16) unsigned short Ks[2][4096];
  __shared__ __align__(16) unsigned short Vs[2][4096];

  bf16x8 qf[4];
#pragma unroll
  for (int dk = 0; dk < 4; ++dk)
    qf[dk] = *reinterpret_cast<const bf16x8*>(
        &Q[(long)(b * 2048 + q0 + wid * 32 + l) * 1024 + h * 64 + dk * 16 + hi * 8]);

  f32x16 oacc[2];
  oacc[0] = (f32x16)(0.f); oacc[1] = (f32x16)(0.f);
  float lsum = 0.f;

  const int lr = lane >> 3;
  const int c8 = lane & 7;
  const unsigned short* ksrc =
      Kb + (long)(b * 4096 + kvh * 2048 + wid * 8 + lr) * 1024 + h * 64 + c8 * 8;
  const unsigned short* vsrc =
      Vt + (long)((b * 16 + h) * 64 + wid * 8 + lr) * 4096 + kvh * 2048 + c8 * 8;
  const int wk0 = (wid * 8 + lr) * 64 + ((c8 ^ lr) * 8);   // swizzled slot

  u16x8 rk0 = *reinterpret_cast<const u16x8*>(ksrc);
  u16x8 rv0 = *reinterpret_cast<const u16x8*>(vsrc);
  *reinterpret_cast<u16x8*>(&Ks[0][wk0]) = rk0;
  *reinterpret_cast<u16x8*>(&Vs[0][wk0]) = rv0;
  __syncthreads();

  for (int t = 0; t < 32; ++t) {
    const int cur = t & 1;
    if (t < 31) {
      rk0 = *reinterpret_cast<const u16x8*>(ksrc + (long)(t + 1) * 65536);
      rv0 = *reinterpret_cast<const u16x8*>(vsrc + (t + 1) * 64);
    }

    f32x16 s2[2];
    s2[0] = (f32x16)(-MSC); s2[1] = (f32x16)(-MSC);
#pragma unroll
    for (int kvb = 0; kvb < 2; ++kvb) {
#pragma unroll
      for (int dk = 0; dk < 4; ++dk) {
        const int r = kvb * 32 + l;
        bf16x8 kf = *reinterpret_cast<const bf16x8*>(
            &Ks[cur][r * 64 + (((dk * 2 + hi) ^ l7) * 8)]);
        s2[kvb] = __builtin_amdgcn_mfma_f32_32x32x16_bf16(kf, qf[dk], s2[kvb], 0, 0, 0);
      }
    }

    bf16x8 pA[4];
#pragma unroll
    for (int kvb = 0; kvb < 2; ++kvb) {
      float p[16];
      float ps = 0.f;
#pragma unroll
      for (int r = 0; r < 16; ++r) {
        p[r] = __builtin_amdgcn_exp2f(s2[kvb][r]);
        ps += p[r];
      }
      lsum += ps;
      unsigned int pk[8];
#pragma unroll
      for (int i = 0; i < 8; ++i) pk[i] = packtrunc(p[2 * i], p[2 * i + 1]);
      asm("v_permlane32_swap_b32 %0, %1" : "+v"(pk[0]), "+v"(pk[2]));
      asm("v_permlane32_swap_b32 %0, %1" : "+v"(pk[1]), "+v"(pk[3]));
      asm("v_permlane32_swap_b32 %0, %1" : "+v"(pk[4]), "+v"(pk[6]));
      asm("v_permlane32_swap_b32 %0, %1" : "+v"(pk[5]), "+v"(pk[7]));
      u32x4 w0 = {pk[0], pk[1], pk[2], pk[3]};
      u32x4 w1 = {pk[4], pk[5], pk[6], pk[7]};
      pA[kvb * 2] = __builtin_bit_cast(bf16x8, w0);
      pA[kvb * 2 + 1] = __builtin_bit_cast(bf16x8, w1);
    }

#pragma unroll
    for (int dblk = 0; dblk < 2; ++dblk) {
      const int r = dblk * 32 + l;
#pragma unroll
      for (int seg = 0; seg < 4; ++seg) {
        bf16x8 vf = *reinterpret_cast<const bf16x8*>(
            &Vs[cur][r * 64 + (((seg * 2 + hi) ^ l7) * 8)]);
        oacc[dblk] = __builtin_amdgcn_mfma_f32_32x32x16_bf16(pA[seg], vf, oacc[dblk], 0, 0, 0);
      }
    }

    if (t < 31) {
      *reinterpret_cast<u16x8*>(&Ks[cur ^ 1][wk0]) = rk0;
      *reinterpret_cast<u16x8*>(&Vs[cur ^ 1][wk0]) = rv0;
      __syncthreads();
    }
  }

  // epilogue: self-normalized partial O (bf16) + partial lsum
  lsum += __shfl_xor(lsum, 32);
  const float inv = 1.0f / lsum;
  if (hi == 0)
    Lp[kvh * 65536 + (b * 2048 + q0 + wid * 32 + l) * 16 + h] = lsum;
  unsigned short* Oh = Op + (long)kvh * 4194304;
#pragma unroll
  for (int reg = 0; reg < 16; ++reg) {
    const int qrow = (reg & 3) + 8 * (reg >> 2) + 4 * hi;
    const float ivr = __shfl(inv, qrow, 64);
    const long rbase = (long)(b * 2048 + q0 + wid * 32 + qrow) * 1024 + h * 64;
    Oh[rbase + l] = f2bf(oacc[0][reg] * ivr);
    Oh[rbase + 32 + l] = f2bf(oacc[1][reg] * ivr);
  }
}

// ---------------- combine the two KV halves ---------------------------------
__global__ void combine(const unsigned short* __restrict__ Op,
                        const float* __restrict__ Lp,
                        unsigned short* __restrict__ AO) {
  const long i = ((long)blockIdx.x * 256 + threadIdx.x) * 8;
  const int row = (int)(i >> 10);
  const int h = ((int)(i >> 6)) & 15;
  const float l0 = Lp[row * 16 + h];
  const float l1 = Lp[65536 + row * 16 + h];
  const float inv = 1.0f / (l0 + l1);
  const float w0 = l0 * inv, w1 = l1 * inv;
  u16x8 a = *reinterpret_cast<const u16x8*>(Op + i);
  u16x8 bq = *reinterpret_cast<const u16x8*>(Op + 4194304 + i);
  u16x8 o;
#pragma unroll
  for (int j = 0; j < 8; ++j)
    o[j] = f2bf(bf2f(a[j]) * w0 + bf2f(bq[j]) * w1);
  *reinterpret_cast<u16x8*>(AO + i) = o;
}

// ---------------- launcher ----------------
extern "C" void kernel_launch(void* const* d_in, const int* in_sizes, int n_in,
                              void* d_out, int out_size, void* d_ws, size_t ws_size,
                              hipStream_t stream) {
  const float* query = (const float*)d_in[0];
  const float* context = (const float*)d_in[1];
  const float* Wq = (const float*)d_in[2];
  const float* Wk = (const float*)d_in[3];
  const float* Wv = (const float*)d_in[4];
  const float* Wo = (const float*)d_in[5];

  char* ws = (char*)d_ws;
  unsigned short* qb = (unsigned short*)(ws);              // 4096x1024 bf16 (8 MB)
  unsigned short* cb = (unsigned short*)(ws + 8388608);    // 8192x1024 (16 MB)
  unsigned short* wqb = (unsigned short*)(ws + 25165824);  // 1024x1024 (2 MB)
  unsigned short* wkb = (unsigned short*)(ws + 27262976);
  unsigned short* wvb = (unsigned short*)(ws + 29360128);
  unsigned short* wob = (unsigned short*)(ws + 31457280);
  unsigned short* Qb = (unsigned short*)(ws + 33554432);   // 4096x1024 (pre-scaled by SC)
  unsigned short* Kb = (unsigned short*)(ws + 41943040);   // 8192x1024
  unsigned short* Vt = (unsigned short*)(ws + 58720256);   // (2,16,64,4096)
  // flash scratch (regions dead after proj):
  unsigned short* Op = (unsigned short*)(ws + 8388608);    // 2 x 8 MB bf16 partial O (cb)
  float* Lp = (float*)(ws + 25165824);                     // 2 x 256 KB lsum (wqb)
  unsigned short* AO = qb;                                 // combined attn out (qb)

  cast_all<<<16384, 256, 0, stream>>>(query, context, Wq, Wk, Wv, Wo,
                                      qb, cb, wqb, wkb, wvb, wob);
  proj_q<<<256, 512, 0, stream>>>(qb, wqb, Qb);
  proj_kv<<<512, 512, 0, stream>>>(cb, wkb, wvb, Kb, Vt);
  flash_attn<<<512, 512, 0, stream>>>(Qb, Kb, Vt, Op, Lp);
  combine<<<2048, 256, 0, stream>>>(Op, Lp, AO);
  gemm_o<<<512, 512, 0, stream>>>(AO, wob, (float*)d_out);
}

// Round 20
// 175.948 us; speedup vs baseline: 1.0266x; 1.0266x over previous
//
#include <hip/hip_runtime.h>

typedef __attribute__((__ext_vector_type__(4))) float f32x4;
typedef __attribute__((__ext_vector_type__(16))) float f32x16;
typedef __attribute__((__ext_vector_type__(8))) __bf16 bf16x8;
typedef __attribute__((__ext_vector_type__(8))) unsigned short u16x8;
typedef __attribute__((__ext_vector_type__(4))) unsigned int u32x4;

#define AS1 __attribute__((address_space(1)))
#define AS3 __attribute__((address_space(3)))

#define SC 0.18033688011112042f   // log2(e)/8
#define MSC 5.7707801635558535f   // 32*SC

__device__ __forceinline__ unsigned short f2bf(float f) {
  unsigned int u = __float_as_uint(f);
  u += 0x7FFFu + ((u >> 16) & 1u);   // RNE
  return (unsigned short)(u >> 16);
}
__device__ __forceinline__ float bf2f(unsigned short u) {
  return __uint_as_float((unsigned int)u << 16);
}
__device__ __forceinline__ unsigned int packtrunc(float lo, float hi) {
  return (__float_as_uint(hi) & 0xFFFF0000u) | (__float_as_uint(lo) >> 16);
}

// ---------------- fused cast fp32 -> bf16 (all 6 tensors, one dispatch) -----
__global__ void cast_all(const float* __restrict__ q, const float* __restrict__ c,
                         const float* __restrict__ wq, const float* __restrict__ wk,
                         const float* __restrict__ wv, const float* __restrict__ wo,
                         unsigned short* __restrict__ qb, unsigned short* __restrict__ cb,
                         unsigned short* __restrict__ wqb, unsigned short* __restrict__ wkb,
                         unsigned short* __restrict__ wvb, unsigned short* __restrict__ wob) {
  const int blk = blockIdx.x;
  const float* s; unsigned short* d; int off;
  if (blk < 4096)        { s = q;  d = qb;  off = blk; }
  else if (blk < 12288)  { s = c;  d = cb;  off = blk - 4096; }
  else if (blk < 13312)  { s = wq; d = wqb; off = blk - 12288; }
  else if (blk < 14336)  { s = wk; d = wkb; off = blk - 13312; }
  else if (blk < 15360)  { s = wv; d = wvb; off = blk - 14336; }
  else                   { s = wo; d = wob; off = blk - 15360; }
  const long i = ((long)off * 256 + threadIdx.x) * 4;
  float4 v = *reinterpret_cast<const float4*>(s + i);
  ushort4 o;
  o.x = f2bf(v.x); o.y = f2bf(v.y); o.z = f2bf(v.z); o.w = f2bf(v.w);
  *reinterpret_cast<ushort4*>(d + i) = o;
}

// ---------------- shared 128x128x32 GEMM core, 512 threads (8 waves 2x4) ----
__device__ __forceinline__ void gemm_core(const unsigned short* __restrict__ A,
                                          const unsigned short* __restrict__ Bt,
                                          unsigned short* As, unsigned short* Bs,
                                          int m0, int n0, f32x4 acc[4][2]) {
  const int tid = threadIdx.x, lane = tid & 63, wid = tid >> 6;
  const int fr = lane & 15, fg = lane >> 4;
  const int wr = wid >> 2, wc = wid & 3;
  const int srow = tid >> 2;            // 0..127
  const int scol = (tid & 3) * 8;       // 4 chunks x 8 shorts
  const unsigned short* a0 = A + (long)(m0 + srow) * 1024 + scol;
  const unsigned short* b0 = Bt + (long)(n0 + srow) * 1024 + scol;

  for (int k0 = 0; k0 < 1024; k0 += 32) {
    __builtin_amdgcn_global_load_lds((const AS1 void*)(a0 + k0),
                                     (AS3 void*)(As + wid * 512), 16, 0, 0);
    __builtin_amdgcn_global_load_lds((const AS1 void*)(b0 + k0),
                                     (AS3 void*)(Bs + wid * 512), 16, 0, 0);
    __syncthreads();
    bf16x8 af[4], bfr[2];
#pragma unroll
    for (int m = 0; m < 4; ++m)
      af[m] = *reinterpret_cast<const bf16x8*>(&As[(wr * 64 + m * 16 + fr) * 32 + fg * 8]);
#pragma unroll
    for (int n = 0; n < 2; ++n)
      bfr[n] = *reinterpret_cast<const bf16x8*>(&Bs[(wc * 32 + n * 16 + fr) * 32 + fg * 8]);
#pragma unroll
    for (int m = 0; m < 4; ++m)
#pragma unroll
      for (int n = 0; n < 2; ++n)
        acc[m][n] = __builtin_amdgcn_mfma_f32_16x16x32_bf16(af[m], bfr[n], acc[m][n], 0, 0, 0);
    __syncthreads();
  }
}

// ---------------- fused Q/K/V projections (one dispatch, 1280 blocks) -------
// Q output is PRE-SCALED by SC (folded softmax scale).
__global__ __launch_bounds__(512) void proj_fused(const unsigned short* __restrict__ qb,
                                                  const unsigned short* __restrict__ cb,
                                                  const unsigned short* __restrict__ wqb,
                                                  const unsigned short* __restrict__ wkb,
                                                  const unsigned short* __restrict__ wvb,
                                                  unsigned short* __restrict__ Qb,
                                                  unsigned short* __restrict__ Kb,
                                                  unsigned short* __restrict__ Vt) {
  const int raw = blockIdx.x;
  const int bid = (raw & 7) * 160 + (raw >> 3);   // XCD-contiguous remap (1280 = 8*160)
  const unsigned short *A, *Bt; unsigned short* C; int mode, loc;
  float oscale = 1.0f;
  if (bid < 256)      { A = qb; Bt = wqb; C = Qb; mode = 0; loc = bid; oscale = SC; }
  else if (bid < 768) { A = cb; Bt = wkb; C = Kb; mode = 0; loc = bid - 256; }
  else                { A = cb; Bt = wvb; C = Vt; mode = 2; loc = bid - 768; }
  const int m0 = (loc >> 3) << 7, n0 = (loc & 7) << 7;

  __shared__ __align__(16) unsigned short As[128 * 32];
  __shared__ __align__(16) unsigned short Bs[128 * 32];
  f32x4 acc[4][2];
#pragma unroll
  for (int m = 0; m < 4; ++m)
#pragma unroll
    for (int n = 0; n < 2; ++n) acc[m][n] = {0.f, 0.f, 0.f, 0.f};

  gemm_core(A, Bt, As, Bs, m0, n0, acc);

  const int lane = threadIdx.x & 63, wid = threadIdx.x >> 6;
  const int fr = lane & 15, fg = lane >> 4, wr = wid >> 2, wc = wid & 3;
  if (mode == 0) {
#pragma unroll
    for (int m = 0; m < 4; ++m) {
      const int row = m0 + wr * 64 + m * 16 + fg * 4;
#pragma unroll
      for (int n = 0; n < 2; ++n) {
        const int col = n0 + wc * 32 + n * 16 + fr;
#pragma unroll
        for (int r = 0; r < 4; ++r)
          C[(long)(row + r) * 1024 + col] = f2bf(acc[m][n][r] * oscale);
      }
    }
  } else {
#pragma unroll
    for (int m = 0; m < 4; ++m) {
      const int row = m0 + wr * 64 + m * 16 + fg * 4;  // token row in B*Tc
      const int bb = row >> 12, t = row & 4095;
#pragma unroll
      for (int n = 0; n < 2; ++n) {
        const int col = n0 + wc * 32 + n * 16 + fr;    // h*64 + d
        ushort4 o;
        o.x = f2bf(acc[m][n][0]); o.y = f2bf(acc[m][n][1]);
        o.z = f2bf(acc[m][n][2]); o.w = f2bf(acc[m][n][3]);
        *reinterpret_cast<ushort4*>(&C[((long)(bb * 1024 + col)) * 4096 + t]) = o;
      }
    }
  }
}

// ---------------- O projection, 128x64 tiles (fp32 out -> d_out) ------------
// 512 blocks = 2/CU: 2x TLP on a latency-bound kernel.
__global__ __launch_bounds__(512) void gemm_o(const unsigned short* __restrict__ A,
                                              const unsigned short* __restrict__ Bt,
                                              float* __restrict__ C) {
  const int raw = blockIdx.x;
  const int bid = (raw & 7) * 64 + (raw >> 3);    // XCD remap (512 = 8*64)
  const int m0 = (bid >> 4) << 7;                 // 32 m-tiles of 128
  const int n0 = (bid & 15) << 6;                 // 16 n-tiles of 64
  __shared__ __align__(16) unsigned short As[128 * 32];
  __shared__ __align__(16) unsigned short Bs[64 * 32];
  const int tid = threadIdx.x, lane = tid & 63, wid = tid >> 6;
  const int fr = lane & 15, fg = lane >> 4;
  const int wr = wid >> 2, wc = wid & 3;
  const int srow = tid >> 2;            // 0..127
  const int scol = (tid & 3) * 8;
  const unsigned short* a0 = A + (long)(m0 + srow) * 1024 + scol;
  const unsigned short* b0 = Bt + (long)(n0 + srow) * 1024 + scol;  // used iff wid<4

  f32x4 acc[4];
#pragma unroll
  for (int m = 0; m < 4; ++m) acc[m] = {0.f, 0.f, 0.f, 0.f};

  for (int k0 = 0; k0 < 1024; k0 += 32) {
    __builtin_amdgcn_global_load_lds((const AS1 void*)(a0 + k0),
                                     (AS3 void*)(As + wid * 512), 16, 0, 0);
    if (wid < 4)
      __builtin_amdgcn_global_load_lds((const AS1 void*)(b0 + k0),
                                       (AS3 void*)(Bs + wid * 512), 16, 0, 0);
    __syncthreads();
    bf16x8 af[4], bfr;
#pragma unroll
    for (int m = 0; m < 4; ++m)
      af[m] = *reinterpret_cast<const bf16x8*>(&As[(wr * 64 + m * 16 + fr) * 32 + fg * 8]);
    bfr = *reinterpret_cast<const bf16x8*>(&Bs[(wc * 16 + fr) * 32 + fg * 8]);
#pragma unroll
    for (int m = 0; m < 4; ++m)
      acc[m] = __builtin_amdgcn_mfma_f32_16x16x32_bf16(af[m], bfr, acc[m], 0, 0, 0);
    __syncthreads();
  }

#pragma unroll
  for (int m = 0; m < 4; ++m) {
    const int row = m0 + wr * 64 + m * 16 + fg * 4;
    const int col = n0 + wc * 16 + fr;
#pragma unroll
    for (int r = 0; r < 4; ++r)
      C[(long)(row + r) * 1024 + col] = acc[m][r];
  }
}

// ---------------- flash attention: QBLK=256 (8 waves), reg-staged, dbuf -----
// (R13 structure, replay-stable across R13-R18; no setprio — R19 showed it
// makes graph replays nondeterministic in this barrier structure.)
__global__ __launch_bounds__(512, 4) void flash_attn(const unsigned short* __restrict__ Q,
                                                     const unsigned short* __restrict__ Kb,
                                                     const unsigned short* __restrict__ Vt,
                                                     unsigned short* __restrict__ Op,
                                                     float* __restrict__ Lp) {
  const int tid = threadIdx.x, lane = tid & 63, wid = tid >> 6;
  const int raw = (int)blockIdx.x;
  const int blk = (raw & 7) * 64 + (raw >> 3);    // XCD remap (512 = 8*64)
  const int kvh = blk & 1;
  const int qt = (blk >> 1) & 7;
  const int h = (blk >> 4) & 15;
  const int b = blk >> 8;
  const int q0 = qt * 256;
  const int l = lane & 31, hi = lane >> 5, l7 = l & 7;

  __shared__ __align__(16) unsigned short Ks[2][4096];
  __shared__ __align__(16) unsigned short Vs[2][4096];

  bf16x8 qf[4];
#pragma unroll
  for (int dk = 0; dk < 4; ++dk)
    qf[dk] = *reinterpret_cast<const bf16x8*>(
        &Q[(long)(b * 2048 + q0 + wid * 32 + l) * 1024 + h * 64 + dk * 16 + hi * 8]);

  f32x16 oacc[2];
  oacc[0] = (f32x16)(0.f); oacc[1] = (f32x16)(0.f);
  float lsum = 0.f;

  const int lr = lane >> 3;
  const int c8 = lane & 7;
  const unsigned short* ksrc =
      Kb + (long)(b * 4096 + kvh * 2048 + wid * 8 + lr) * 1024 + h * 64 + c8 * 8;
  const unsigned short* vsrc =
      Vt + (long)((b * 16 + h) * 64 + wid * 8 + lr) * 4096 + kvh * 2048 + c8 * 8;
  const int wk0 = (wid * 8 + lr) * 64 + ((c8 ^ lr) * 8);   // swizzled slot

  u16x8 rk0 = *reinterpret_cast<const u16x8*>(ksrc);
  u16x8 rv0 = *reinterpret_cast<const u16x8*>(vsrc);
  *reinterpret_cast<u16x8*>(&Ks[0][wk0]) = rk0;
  *reinterpret_cast<u16x8*>(&Vs[0][wk0]) = rv0;
  __syncthreads();

  for (int t = 0; t < 32; ++t) {
    const int cur = t & 1;
    if (t < 31) {
      rk0 = *reinterpret_cast<const u16x8*>(ksrc + (long)(t + 1) * 65536);
      rv0 = *reinterpret_cast<const u16x8*>(vsrc + (t + 1) * 64);
    }

    f32x16 s2[2];
    s2[0] = (f32x16)(-MSC); s2[1] = (f32x16)(-MSC);
#pragma unroll
    for (int kvb = 0; kvb < 2; ++kvb) {
#pragma unroll
      for (int dk = 0; dk < 4; ++dk) {
        const int r = kvb * 32 + l;
        bf16x8 kf = *reinterpret_cast<const bf16x8*>(
            &Ks[cur][r * 64 + (((dk * 2 + hi) ^ l7) * 8)]);
        s2[kvb] = __builtin_amdgcn_mfma_f32_32x32x16_bf16(kf, qf[dk], s2[kvb], 0, 0, 0);
      }
    }

    bf16x8 pA[4];
#pragma unroll
    for (int kvb = 0; kvb < 2; ++kvb) {
      float p[16];
      float ps = 0.f;
#pragma unroll
      for (int r = 0; r < 16; ++r) {
        p[r] = __builtin_amdgcn_exp2f(s2[kvb][r]);
        ps += p[r];
      }
      lsum += ps;
      unsigned int pk[8];
#pragma unroll
      for (int i = 0; i < 8; ++i) pk[i] = packtrunc(p[2 * i], p[2 * i + 1]);
      asm("v_permlane32_swap_b32 %0, %1" : "+v"(pk[0]), "+v"(pk[2]));
      asm("v_permlane32_swap_b32 %0, %1" : "+v"(pk[1]), "+v"(pk[3]));
      asm("v_permlane32_swap_b32 %0, %1" : "+v"(pk[4]), "+v"(pk[6]));
      asm("v_permlane32_swap_b32 %0, %1" : "+v"(pk[5]), "+v"(pk[7]));
      u32x4 w0 = {pk[0], pk[1], pk[2], pk[3]};
      u32x4 w1 = {pk[4], pk[5], pk[6], pk[7]};
      pA[kvb * 2] = __builtin_bit_cast(bf16x8, w0);
      pA[kvb * 2 + 1] = __builtin_bit_cast(bf16x8, w1);
    }

#pragma unroll
    for (int dblk = 0; dblk < 2; ++dblk) {
      const int r = dblk * 32 + l;
#pragma unroll
      for (int seg = 0; seg < 4; ++seg) {
        bf16x8 vf = *reinterpret_cast<const bf16x8*>(
            &Vs[cur][r * 64 + (((seg * 2 + hi) ^ l7) * 8)]);
        oacc[dblk] = __builtin_amdgcn_mfma_f32_32x32x16_bf16(pA[seg], vf, oacc[dblk], 0, 0, 0);
      }
    }

    if (t < 31) {
      *reinterpret_cast<u16x8*>(&Ks[cur ^ 1][wk0]) = rk0;
      *reinterpret_cast<u16x8*>(&Vs[cur ^ 1][wk0]) = rv0;
      __syncthreads();
    }
  }

  // epilogue: self-normalized partial O (bf16) + partial lsum
  lsum += __shfl_xor(lsum, 32);
  const float inv = 1.0f / lsum;
  if (hi == 0)
    Lp[kvh * 65536 + (b * 2048 + q0 + wid * 32 + l) * 16 + h] = lsum;
  unsigned short* Oh = Op + (long)kvh * 4194304;
#pragma unroll
  for (int reg = 0; reg < 16; ++reg) {
    const int qrow = (reg & 3) + 8 * (reg >> 2) + 4 * hi;
    const float ivr = __shfl(inv, qrow, 64);
    const long rbase = (long)(b * 2048 + q0 + wid * 32 + qrow) * 1024 + h * 64;
    Oh[rbase + l] = f2bf(oacc[0][reg] * ivr);
    Oh[rbase + 32 + l] = f2bf(oacc[1][reg] * ivr);
  }
}

// ---------------- combine the two KV halves ---------------------------------
__global__ void combine(const unsigned short* __restrict__ Op,
                        const float* __restrict__ Lp,
                        unsigned short* __restrict__ AO) {
  const long i = ((long)blockIdx.x * 256 + threadIdx.x) * 8;
  const int row = (int)(i >> 10);
  const int h = ((int)(i >> 6)) & 15;
  const float l0 = Lp[row * 16 + h];
  const float l1 = Lp[65536 + row * 16 + h];
  const float inv = 1.0f / (l0 + l1);
  const float w0 = l0 * inv, w1 = l1 * inv;
  u16x8 a = *reinterpret_cast<const u16x8*>(Op + i);
  u16x8 bq = *reinterpret_cast<const u16x8*>(Op + 4194304 + i);
  u16x8 o;
#pragma unroll
  for (int j = 0; j < 8; ++j)
    o[j] = f2bf(bf2f(a[j]) * w0 + bf2f(bq[j]) * w1);
  *reinterpret_cast<u16x8*>(AO + i) = o;
}

// ---------------- launcher ----------------
extern "C" void kernel_launch(void* const* d_in, const int* in_sizes, int n_in,
                              void* d_out, int out_size, void* d_ws, size_t ws_size,
                              hipStream_t stream) {
  const float* query = (const float*)d_in[0];
  const float* context = (const float*)d_in[1];
  const float* Wq = (const float*)d_in[2];
  const float* Wk = (const float*)d_in[3];
  const float* Wv = (const float*)d_in[4];
  const float* Wo = (const float*)d_in[5];

  char* ws = (char*)d_ws;
  unsigned short* qb = (unsigned short*)(ws);              // 4096x1024 bf16 (8 MB)
  unsigned short* cb = (unsigned short*)(ws + 8388608);    // 8192x1024 (16 MB)
  unsigned short* wqb = (unsigned short*)(ws + 25165824);  // 1024x1024 (2 MB)
  unsigned short* wkb = (unsigned short*)(ws + 27262976);
  unsigned short* wvb = (unsigned short*)(ws + 29360128);
  unsigned short* wob = (unsigned short*)(ws + 31457280);
  unsigned short* Qb = (unsigned short*)(ws + 33554432);   // 4096x1024 (pre-scaled by SC)
  unsigned short* Kb = (unsigned short*)(ws + 41943040);   // 8192x1024
  unsigned short* Vt = (unsigned short*)(ws + 58720256);   // (2,16,64,4096)
  // flash scratch (regions dead after proj):
  unsigned short* Op = (unsigned short*)(ws + 8388608);    // 2 x 8 MB bf16 partial O (cb)
  float* Lp = (float*)(ws + 25165824);                     // 2 x 256 KB lsum (wqb)
  unsigned short* AO = qb;                                 // combined attn out (qb)

  cast_all<<<16384, 256, 0, stream>>>(query, context, Wq, Wk, Wv, Wo,
                                      qb, cb, wqb, wkb, wvb, wob);
  proj_fused<<<1280, 512, 0, stream>>>(qb, cb, wqb, wkb, wvb, Qb, Kb, Vt);
  flash_attn<<<512, 512, 0, stream>>>(Qb, Kb, Vt, Op, Lp);
  combine<<<2048, 256, 0, stream>>>(Op, Lp, AO);
  gemm_o<<<512, 512, 0, stream>>>(AO, wob, (float*)d_out);
}